// Round 1
// baseline (79315.448 us; speedup 1.0000x reference)
//
#include <hip/hip_runtime.h>
#include <hip/hip_bf16.h>
#include <math.h>

// Multilayer GRU: B=32, S=512, H=1024, L=3, O=1024.
// Design: persistent per-layer kernel, 128 blocks, manual grid barriers.
//   blocks 0..63  : z-cols 16j (phase1) and g-cols 16j + h update (phase2)
//   blocks 64..127: r-cols 16j (phase1), publish rh = sigmoid(r)*h_prev (bf16)
// Input projections fused as extra K (K=2048 over [h ; x_t]).
// bf16 MFMA 16x16x32, fp32 accum, fp32 master h state.

#define BB 32
#define SS 512
#define HH 1024
#define LL 3
#define OO 1024
#define SH (SS*HH)
#define NBLK 128

typedef __attribute__((ext_vector_type(8))) short short8;
typedef __attribute__((ext_vector_type(4))) float float4v;

__device__ __forceinline__ unsigned short f2bf(float f) {
  union { float f; unsigned int u; } v; v.f = f;
  return (unsigned short)((v.u + 0x7FFFu + ((v.u >> 16) & 1u)) >> 16);
}

__global__ void convert_bf16(const float* __restrict__ src,
                             unsigned short* __restrict__ dst, int n) {
  int stride = gridDim.x * blockDim.x;
  for (int i = blockIdx.x * blockDim.x + threadIdx.x; i < n; i += stride)
    dst[i] = f2bf(src[i]);
}

// device-wide barrier: one counter slot per barrier instance (slots pre-zeroed)
__device__ __forceinline__ void gbar(int* bar, int idx, int n) {
  __syncthreads();
  if (threadIdx.x == 0) {
    __threadfence();
    atomicAdd(&bar[idx], 1);
    while (__hip_atomic_load(&bar[idx], __ATOMIC_RELAXED,
                             __HIP_MEMORY_SCOPE_AGENT) < n)
      __builtin_amdgcn_s_sleep(1);
  }
  __syncthreads();
  __threadfence();
}

__launch_bounds__(256)
__global__ void gru_layer(
    const unsigned short* __restrict__ xin,   // [B,S,H] bf16 (layer input seq)
    unsigned short* __restrict__ yout,        // [B,S,H] bf16 (layer output seq)
    const unsigned short* __restrict__ Wzh, const unsigned short* __restrict__ Wzx,
    const unsigned short* __restrict__ Wrh, const unsigned short* __restrict__ Wrx,
    const unsigned short* __restrict__ Wgh, const unsigned short* __restrict__ Wgx,
    const float* __restrict__ bz, const float* __restrict__ br, const float* __restrict__ bg,
    const float* __restrict__ h0,             // base pre-offset by l*H; [b*3072 + c]
    float* __restrict__ hf,                   // [2][B][H] fp32 state
    unsigned short* __restrict__ hb,          // [2][B][H] bf16 broadcast copy
    unsigned short* __restrict__ rh,          // [B][H] bf16 (r * h_prev)
    float* __restrict__ hid_out,              // d_out tail, pre-offset by l*H
    int* __restrict__ bar) {
  const int tid = threadIdx.x;
  const int blk = blockIdx.x;
  const int lane = tid & 63;
  const int wave = tid >> 6;   // 0..3
  const int mt = wave & 1;     // M-tile (rows 0-15 / 16-31)
  const int kh = wave >> 1;    // K-half (0: h/rh part, 1: x part)

  // init h state (32768 values over 32768 threads)
  {
    int g = blk * 256 + tid;
    int b = g >> 10, c = g & 1023;
    float v = h0[b * (LL * HH) + c];
    hf[b * HH + c] = v;
    hb[b * HH + c] = f2bf(v);
  }
  gbar(bar, 0, NBLK);

  const bool role_r = (blk >= 64);
  const int cols0 = (role_r ? (blk - 64) : blk) * 16;
  const unsigned short* Wh1 = role_r ? Wrh : Wzh;
  const unsigned short* Wx1 = role_r ? Wrx : Wzx;
  const float* bias1 = role_r ? br : bz;

  const int fcol = lane & 15;        // A-row selector / B-col selector
  const int kg = lane >> 4;          // k-group 0..3 (8 elems each)
  const int arow = mt * 16 + fcol;   // A row (= batch b)
  const int crow0 = mt * 16 + kg * 4; // C row base (q adds 0..3)
  const int ccol = cols0 + fcol;     // C col (= W row)

  __shared__ float red[2][64][4];

  float zreg[4] = {0, 0, 0, 0};

  for (int t = 0; t < SS; ++t) {
    const int cur = t & 1, nxt = cur ^ 1;
    const unsigned short* hbc = hb + cur * (BB * HH);
    const float* hfc = hf + cur * (BB * HH);

    // ---------------- phase 1: z (blocks<64) / r->rh (blocks>=64) ----------
    {
      float4v a0 = {0, 0, 0, 0}, a1 = {0, 0, 0, 0};
      const unsigned short* ab;
      const unsigned short* wb;
      if (kh == 0) {
        ab = hbc + arow * HH + kg * 8;
        wb = Wh1 + (size_t)ccol * HH + kg * 8;
      } else {
        ab = xin + (size_t)arow * SH + t * HH + kg * 8;
        wb = Wx1 + (size_t)ccol * HH + kg * 8;
      }
#pragma unroll 8
      for (int ks = 0; ks < 32; ks += 2) {
        short8 av = *(const short8*)(ab + ks * 32);
        short8 wv = *(const short8*)(wb + ks * 32);
        a0 = __builtin_amdgcn_mfma_f32_16x16x32_bf16(av, wv, a0, 0, 0, 0);
        short8 av2 = *(const short8*)(ab + (ks + 1) * 32);
        short8 wv2 = *(const short8*)(wb + (ks + 1) * 32);
        a1 = __builtin_amdgcn_mfma_f32_16x16x32_bf16(av2, wv2, a1, 0, 0, 0);
      }
      float4v acc;
      acc[0] = a0[0] + a1[0]; acc[1] = a0[1] + a1[1];
      acc[2] = a0[2] + a1[2]; acc[3] = a0[3] + a1[3];
      __syncthreads();
      if (kh == 1) {
        red[mt][lane][0] = acc[0]; red[mt][lane][1] = acc[1];
        red[mt][lane][2] = acc[2]; red[mt][lane][3] = acc[3];
      }
      __syncthreads();
      if (kh == 0) {
        float bsv = bias1[ccol];
#pragma unroll
        for (int q = 0; q < 4; ++q) {
          float p = acc[q] + red[mt][lane][q] + bsv;
          float s = 1.0f / (1.0f + expf(-p));
          if (!role_r) {
            zreg[q] = s;
          } else {
            int row = crow0 + q;
            float hov = hfc[row * HH + ccol];
            rh[row * HH + ccol] = f2bf(s * hov);
          }
        }
      }
    }
    gbar(bar, 1 + 2 * t, NBLK);

    // ---------------- phase 2: g + h update (blocks<64 only) ---------------
    if (!role_r) {
      float4v a0 = {0, 0, 0, 0}, a1 = {0, 0, 0, 0};
      const unsigned short* ab;
      const unsigned short* wb;
      if (kh == 0) {
        ab = rh + arow * HH + kg * 8;
        wb = Wgh + (size_t)ccol * HH + kg * 8;
      } else {
        ab = xin + (size_t)arow * SH + t * HH + kg * 8;
        wb = Wgx + (size_t)ccol * HH + kg * 8;
      }
#pragma unroll 8
      for (int ks = 0; ks < 32; ks += 2) {
        short8 av = *(const short8*)(ab + ks * 32);
        short8 wv = *(const short8*)(wb + ks * 32);
        a0 = __builtin_amdgcn_mfma_f32_16x16x32_bf16(av, wv, a0, 0, 0, 0);
        short8 av2 = *(const short8*)(ab + (ks + 1) * 32);
        short8 wv2 = *(const short8*)(wb + (ks + 1) * 32);
        a1 = __builtin_amdgcn_mfma_f32_16x16x32_bf16(av2, wv2, a1, 0, 0, 0);
      }
      float4v acc;
      acc[0] = a0[0] + a1[0]; acc[1] = a0[1] + a1[1];
      acc[2] = a0[2] + a1[2]; acc[3] = a0[3] + a1[3];
      __syncthreads();
      if (kh == 1) {
        red[mt][lane][0] = acc[0]; red[mt][lane][1] = acc[1];
        red[mt][lane][2] = acc[2]; red[mt][lane][3] = acc[3];
      }
      __syncthreads();
      if (kh == 0) {
        float bgv = bg[ccol];
#pragma unroll
        for (int q = 0; q < 4; ++q) {
          float p = acc[q] + red[mt][lane][q] + bgv;
          float gg = tanhf(p);
          int row = crow0 + q;
          float hov = hfc[row * HH + ccol];
          float hn = zreg[q] * hov + (1.0f - zreg[q]) * gg;
          hf[nxt * (BB * HH) + row * HH + ccol] = hn;
          hb[nxt * (BB * HH) + row * HH + ccol] = f2bf(hn);
          yout[(size_t)row * SH + t * HH + ccol] = f2bf(hn);
          if (t == SS - 1) hid_out[row * (LL * HH) + ccol] = hn;
        }
      }
    }
    gbar(bar, 2 + 2 * t, NBLK);
  }
}

// C[16384,1024] = A[16384,1024](bf16) @ W^T[1024,1024](bf16 rows) + bo
__launch_bounds__(64)
__global__ void out_gemm(const unsigned short* __restrict__ A,
                         const unsigned short* __restrict__ W,
                         const float* __restrict__ bo,
                         float* __restrict__ C) {
  const int lane = threadIdx.x;
  const int nt4 = blockIdx.x & 15;
  const int mt4 = blockIdx.x >> 4;
  const int r0 = mt4 * 64, n0 = nt4 * 64;
  const int fcol = lane & 15, kg = lane >> 4;
  float4v acc[4][4];
#pragma unroll
  for (int i = 0; i < 4; ++i)
#pragma unroll
    for (int j = 0; j < 4; ++j) acc[i][j] = (float4v){0, 0, 0, 0};

  for (int ks = 0; ks < 32; ++ks) {
    short8 a[4], b[4];
#pragma unroll
    for (int i = 0; i < 4; ++i)
      a[i] = *(const short8*)(A + (size_t)(r0 + i * 16 + fcol) * HH + ks * 32 + kg * 8);
#pragma unroll
    for (int j = 0; j < 4; ++j)
      b[j] = *(const short8*)(W + (size_t)(n0 + j * 16 + fcol) * HH + ks * 32 + kg * 8);
#pragma unroll
    for (int i = 0; i < 4; ++i)
#pragma unroll
      for (int j = 0; j < 4; ++j)
        acc[i][j] = __builtin_amdgcn_mfma_f32_16x16x32_bf16(a[i], b[j], acc[i][j], 0, 0, 0);
  }
#pragma unroll
  for (int i = 0; i < 4; ++i)
#pragma unroll
    for (int j = 0; j < 4; ++j)
#pragma unroll
      for (int q = 0; q < 4; ++q) {
        int R = r0 + i * 16 + kg * 4 + q;
        int col = n0 + j * 16 + fcol;
        C[(size_t)R * OO + col] = acc[i][j][q] + bo[col];
      }
}

extern "C" void kernel_launch(void* const* d_in, const int* in_sizes, int n_in,
                              void* d_out, int out_size, void* d_ws, size_t ws_size,
                              hipStream_t stream) {
  (void)in_sizes; (void)n_in; (void)out_size; (void)ws_size;

  const float* x   = (const float*)d_in[0];
  const float* h0  = (const float*)d_in[1];
  const float* Wzx = (const float*)d_in[2];
  const float* bz  = (const float*)d_in[3];
  const float* Wzh = (const float*)d_in[4];
  const float* Wrx = (const float*)d_in[5];
  const float* br  = (const float*)d_in[6];
  const float* Wrh = (const float*)d_in[7];
  const float* Wgx = (const float*)d_in[8];
  const float* bg  = (const float*)d_in[9];
  const float* Wgh = (const float*)d_in[10];
  const float* Wo  = (const float*)d_in[11];
  const float* bo  = (const float*)d_in[12];
  float* out = (float*)d_out;

  // ws layout (~141 MB)
  unsigned short* Wzxb = (unsigned short*)d_ws;         // 6 groups x 3M elems
  unsigned short* Wzhb = Wzxb + 3145728;
  unsigned short* Wrxb = Wzhb + 3145728;
  unsigned short* Wrhb = Wrxb + 3145728;
  unsigned short* Wgxb = Wrhb + 3145728;
  unsigned short* Wghb = Wgxb + 3145728;
  unsigned short* Wob  = Wghb + 3145728;                // 1M elems
  unsigned short* xbf  = Wob + 1048576;                 // 16.7M elems
  unsigned short* yA   = xbf + 16777216;
  unsigned short* yB   = yA + 16777216;
  float* hf            = (float*)(yB + 16777216);       // [2][B][H] fp32
  unsigned short* hb   = (unsigned short*)(hf + 2 * BB * HH);
  unsigned short* rhb  = hb + 2 * BB * HH;
  int* bar             = (int*)(rhb + BB * HH);         // 3 x 1032 slots

  hipMemsetAsync(bar, 0, 3 * 1032 * sizeof(int), stream);

  convert_bf16<<<512, 256, 0, stream>>>(Wzx, Wzxb, 3145728);
  convert_bf16<<<512, 256, 0, stream>>>(Wzh, Wzhb, 3145728);
  convert_bf16<<<512, 256, 0, stream>>>(Wrx, Wrxb, 3145728);
  convert_bf16<<<512, 256, 0, stream>>>(Wrh, Wrhb, 3145728);
  convert_bf16<<<512, 256, 0, stream>>>(Wgx, Wgxb, 3145728);
  convert_bf16<<<512, 256, 0, stream>>>(Wgh, Wghb, 3145728);
  convert_bf16<<<256, 256, 0, stream>>>(Wo, Wob, 1048576);
  convert_bf16<<<2048, 256, 0, stream>>>(x, xbf, 16777216);

  const unsigned short* xins[3] = {xbf, yA, yB};
  unsigned short* youts[3] = {yA, yB, yA};
  for (int l = 0; l < 3; ++l) {
    gru_layer<<<NBLK, 256, 0, stream>>>(
        xins[l], youts[l],
        Wzhb + (size_t)l * 1048576, Wzxb + (size_t)l * 1048576,
        Wrhb + (size_t)l * 1048576, Wrxb + (size_t)l * 1048576,
        Wghb + (size_t)l * 1048576, Wgxb + (size_t)l * 1048576,
        bz + l * 1024, br + l * 1024, bg + l * 1024,
        h0 + l * 1024,
        hf, hb, rhb,
        out + 16777216 + l * 1024,
        bar + l * 1032);
  }

  out_gemm<<<4096, 64, 0, stream>>>(yA, Wob, bo, out);
}

// Round 2
// 51382.031 us; speedup vs baseline: 1.5436x; 1.5436x over previous
//
#include <hip/hip_runtime.h>
#include <hip/hip_bf16.h>
#include <math.h>

// Multilayer GRU: B=32, S=512, H=1024, L=3, O=1024.
// v2: persistent per-layer kernel, 64 blocks, flag-array grid barrier,
// zero cache-invalidating fences (all cross-block data via per-op coherent
// sc0/sc1 accesses), LDS-staged h/x with XOR swizzle, fragment-packed weights.

#define BB 32
#define SS 512
#define HH 1024
#define LL 3
#define OO 1024
#define SH (SS*HH)
#define NBLK 64

typedef __attribute__((ext_vector_type(8))) short short8;
typedef __attribute__((ext_vector_type(4))) float float4v;
typedef unsigned long long u64;
typedef unsigned int u32;
typedef unsigned short u16;

__device__ __forceinline__ u16 f2bf(float f) {
  union { float f; u32 u; } v; v.f = f;
  return (u16)((v.u + 0x7FFFu + ((v.u >> 16) & 1u)) >> 16);
}

__global__ void convert_bf16(const float* __restrict__ src,
                             u16* __restrict__ dst, int n) {
  int stride = gridDim.x * blockDim.x;
  for (int i = blockIdx.x * blockDim.x + threadIdx.x; i < n; i += stride)
    dst[i] = f2bf(src[i]);
}

// Pack W[nmat][1024][1024] (row = out col, col = k) into MFMA B-fragment
// stream: dst[(nb*32+ks)*512 + lane*8 + j] = W[nb*16+fcol][ks*32+kg*8+j],
// lane = kg*16+fcol. A wave's frag load becomes base + lane*8 (coalesced).
__global__ void pack_w(const float* __restrict__ src, u16* __restrict__ dst,
                       int nmat) {
  int stride = gridDim.x * blockDim.x;
  int total = nmat * 1048576;
  for (int i = blockIdx.x * blockDim.x + threadIdx.x; i < total; i += stride) {
    int m = i >> 20, e = i & 1048575;
    int row = e >> 10, k = e & 1023;
    int lane = ((k >> 3) & 3) * 16 + (row & 15);
    int di = ((row >> 4) * 32 + (k >> 5)) * 512 + lane * 8 + (k & 7);
    dst[m * 1048576 + di] = f2bf(src[i]);
  }
}

// coherent (device-scope, cache-bypassing) 2-byte store
__device__ __forceinline__ void coh_store_u16(u16* p, u16 v) {
  u32 vv = v;
  asm volatile("global_store_short %0, %1, off sc0 sc1"
               :: "v"(p), "v"(vv) : "memory");
}

// flag-array grid barrier: each block publishes its phase counter; wave 0
// polls all 64 flags lane-parallel. __syncthreads() drains vmcnt (release).
__device__ __forceinline__ void gbar(int* flags, int blk, int lane, int wave,
                                     int target) {
  __syncthreads();
  if (wave == 0) {
    if (lane == 0)
      __hip_atomic_store(flags + blk, target, __ATOMIC_RELAXED,
                         __HIP_MEMORY_SCOPE_AGENT);
    asm volatile("" ::: "memory");
    int f;
    do {
      f = __hip_atomic_load(flags + lane, __ATOMIC_RELAXED,
                            __HIP_MEMORY_SCOPE_AGENT);
    } while (!__all(f >= target));
  }
  __syncthreads();
}

#define MFMA16(a, b, c) __builtin_amdgcn_mfma_f32_16x16x32_bf16(a, b, c, 0, 0, 0)

__launch_bounds__(256)
__global__ void gru_layer(
    const u16* __restrict__ xin,   // [B,S,H] bf16 (== yout buffer, see notes)
    u16* __restrict__ yout,
    const u16* __restrict__ Pzh, const u16* __restrict__ Pzx,
    const u16* __restrict__ Prh, const u16* __restrict__ Prx,
    const u16* __restrict__ Pgh, const u16* __restrict__ Pgx,
    const float* __restrict__ bz, const float* __restrict__ br,
    const float* __restrict__ bg,
    const float* __restrict__ h0,  // pre-offset by l*H; row stride L*H
    u16* __restrict__ hb,          // [B][H] bf16, coherent traffic only
    u16* __restrict__ rh,          // [B][H] bf16, coherent traffic only
    float* __restrict__ hid_out,   // pre-offset by l*H; row stride L*H
    int* __restrict__ flags) {
  __shared__ char hstage[65536];   // h (phase1) / r*h (phase2), swizzled
  __shared__ char xstage[65536];   // x_t, swizzled, lives across both phases
  __shared__ float redz[4][2][64]; // [q][mt][lane] scalar arrays: no conflicts
  __shared__ float redr[4][2][64];
  __shared__ float redg[4][2][64];

  const int tid = threadIdx.x;
  const int blk = blockIdx.x;
  const int lane = tid & 63;
  const int wave = tid >> 6;   // 4 waves
  const int mt = wave & 1;     // M-tile: rows 0-15 / 16-31
  const int kh = wave >> 1;    // K-half: 0 = h-side (LDS hstage), 1 = x-side
  const int fcol = lane & 15;
  const int kg = lane >> 4;
  const int arow = mt * 16 + fcol;
  const int crow0 = mt * 16 + kg * 4;
  const int colZ = blk * 16 + fcol;

  // packed-weight fragment stream bases (include lane offset)
  const u16* w1a = (kh ? Pzx : Pzh) + blk * 16384 + lane * 8;  // z
  const u16* w1b = (kh ? Prx : Prh) + blk * 16384 + lane * 8;  // r
  const u16* w2  = (kh ? Pgx : Pgh) + blk * 16384 + lane * 8;  // g

  // own-column h state + z + biases live in kh0 lanes' registers
  float hreg[4] = {0, 0, 0, 0}, zreg[4] = {0, 0, 0, 0};
  float bzv = 0.f, brv = 0.f, bgv = 0.f;
  if (kh == 0) {
#pragma unroll
    for (int q = 0; q < 4; ++q)
      hreg[q] = h0[(crow0 + q) * (LL * HH) + colZ];
    bzv = bz[colZ]; brv = br[colZ]; bgv = bg[colZ];
  }

  for (int t = 0; t < SS; ++t) {
    // ---------------- stage h(t) + x(t) into LDS -------------------------
    if (t == 0) {
#pragma unroll
      for (int j = 0; j < 32; ++j) {
        int w = j * 256 + tid;                 // 8B word index
        int row = w >> 8, c4 = (w & 255) * 4;
        const float* s = h0 + row * (LL * HH) + c4;
        u64 pk = (u64)f2bf(s[0]) | ((u64)f2bf(s[1]) << 16) |
                 ((u64)f2bf(s[2]) << 32) | ((u64)f2bf(s[3]) << 48);
        int byte = w * 8, r2 = byte >> 11;
        *(u64*)(hstage + (byte ^ ((r2 & 7) << 4))) = pk;
      }
    } else {
      u64 tmp[32];
      const u64* src = (const u64*)hb;
#pragma unroll
      for (int j = 0; j < 32; ++j)
        tmp[j] = __hip_atomic_load(src + j * 256 + tid, __ATOMIC_RELAXED,
                                   __HIP_MEMORY_SCOPE_AGENT);
#pragma unroll
      for (int j = 0; j < 32; ++j) {
        int w = j * 256 + tid;
        int byte = w * 8, r2 = byte >> 11;
        *(u64*)(hstage + (byte ^ ((r2 & 7) << 4))) = tmp[j];
      }
    }
    {
#pragma unroll
      for (int j = 0; j < 32; ++j) {
        int w = j * 256 + tid;
        int row = w >> 8, cs = (w & 255) * 4;  // 4 shorts = 8B
        u64 v = *(const u64*)(xin + (size_t)row * SH + t * HH + cs);
        int byte = w * 8, r2 = byte >> 11;
        *(u64*)(xstage + (byte ^ ((r2 & 7) << 4))) = v;
      }
    }
    __syncthreads();

    // ---------------- phase 1: z,r GEMM (K=1024 per kh over [h | x]) -----
    {
      float4v az[2], ar[2];
      az[0] = (float4v){0,0,0,0}; az[1] = (float4v){0,0,0,0};
      ar[0] = (float4v){0,0,0,0}; ar[1] = (float4v){0,0,0,0};
      const char* abase = kh ? xstage : hstage;
      const int swz = (arow & 7) << 4;
      const int rowb = arow << 11;
#pragma unroll
      for (int ks = 0; ks < 32; ++ks) {
        short8 av = *(const short8*)(abase + ((rowb + ks * 64 + kg * 16) ^ swz));
        short8 wz = *(const short8*)(w1a + ks * 512);
        short8 wr = *(const short8*)(w1b + ks * 512);
        az[ks & 1] = MFMA16(av, wz, az[ks & 1]);
        ar[ks & 1] = MFMA16(av, wr, ar[ks & 1]);
      }
      float4v accz, accr;
#pragma unroll
      for (int q = 0; q < 4; ++q) {
        accz[q] = az[0][q] + az[1][q];
        accr[q] = ar[0][q] + ar[1][q];
      }
      if (kh == 1) {
#pragma unroll
        for (int q = 0; q < 4; ++q) {
          redz[q][mt][lane] = accz[q];
          redr[q][mt][lane] = accr[q];
        }
      }
      __syncthreads();
      if (kh == 0) {
#pragma unroll
        for (int q = 0; q < 4; ++q) {
          float pz = accz[q] + redz[q][mt][lane] + bzv;
          float pr = accr[q] + redr[q][mt][lane] + brv;
          float zv = 1.f / (1.f + expf(-pz));
          float rv = 1.f / (1.f + expf(-pr));
          zreg[q] = zv;
          coh_store_u16(rh + (crow0 + q) * HH + colZ, f2bf(rv * hreg[q]));
        }
      }
    }
    gbar(flags, blk, lane, wave, 2 * t + 1);

    // ---------------- stage r*h into hstage ------------------------------
    {
      u64 tmp[32];
      const u64* src = (const u64*)rh;
#pragma unroll
      for (int j = 0; j < 32; ++j)
        tmp[j] = __hip_atomic_load(src + j * 256 + tid, __ATOMIC_RELAXED,
                                   __HIP_MEMORY_SCOPE_AGENT);
#pragma unroll
      for (int j = 0; j < 32; ++j) {
        int w = j * 256 + tid;
        int byte = w * 8, r2 = byte >> 11;
        *(u64*)(hstage + (byte ^ ((r2 & 7) << 4))) = tmp[j];
      }
    }
    __syncthreads();

    // ---------------- phase 2: g GEMM + h update -------------------------
    {
      float4v ag[2];
      ag[0] = (float4v){0,0,0,0}; ag[1] = (float4v){0,0,0,0};
      const char* abase = kh ? xstage : hstage;
      const int swz = (arow & 7) << 4;
      const int rowb = arow << 11;
#pragma unroll
      for (int ks = 0; ks < 32; ++ks) {
        short8 av = *(const short8*)(abase + ((rowb + ks * 64 + kg * 16) ^ swz));
        short8 wg = *(const short8*)(w2 + ks * 512);
        ag[ks & 1] = MFMA16(av, wg, ag[ks & 1]);
      }
      float4v accg;
#pragma unroll
      for (int q = 0; q < 4; ++q) accg[q] = ag[0][q] + ag[1][q];
      if (kh == 1) {
#pragma unroll
        for (int q = 0; q < 4; ++q) redg[q][mt][lane] = accg[q];
      }
      __syncthreads();
      if (kh == 0) {
#pragma unroll
        for (int q = 0; q < 4; ++q) {
          float pg = accg[q] + redg[q][mt][lane] + bgv;
          float gv = tanhf(pg);
          float hn = zreg[q] * hreg[q] + (1.f - zreg[q]) * gv;
          hreg[q] = hn;
          u16 hv = f2bf(hn);
          int row = crow0 + q;
          coh_store_u16(hb + row * HH + colZ, hv);
          yout[(size_t)row * SH + t * HH + colZ] = hv;
          if (t == SS - 1) hid_out[row * (LL * HH) + colZ] = hn;
        }
      }
    }
    gbar(flags, blk, lane, wave, 2 * t + 2);
  }
}

// C[16384,1024] = A[16384,1024](bf16) @ W^T[1024,1024](bf16 rows) + bo
__launch_bounds__(64)
__global__ void out_gemm(const u16* __restrict__ A, const u16* __restrict__ W,
                         const float* __restrict__ bo, float* __restrict__ C) {
  const int lane = threadIdx.x;
  const int nt4 = blockIdx.x & 15;
  const int mt4 = blockIdx.x >> 4;
  const int r0 = mt4 * 64, n0 = nt4 * 64;
  const int fcol = lane & 15, kg = lane >> 4;
  float4v acc[4][4];
#pragma unroll
  for (int i = 0; i < 4; ++i)
#pragma unroll
    for (int j = 0; j < 4; ++j) acc[i][j] = (float4v){0, 0, 0, 0};

  for (int ks = 0; ks < 32; ++ks) {
    short8 a[4], b[4];
#pragma unroll
    for (int i = 0; i < 4; ++i)
      a[i] = *(const short8*)(A + (size_t)(r0 + i * 16 + fcol) * HH + ks * 32 + kg * 8);
#pragma unroll
    for (int j = 0; j < 4; ++j)
      b[j] = *(const short8*)(W + (size_t)(n0 + j * 16 + fcol) * HH + ks * 32 + kg * 8);
#pragma unroll
    for (int i = 0; i < 4; ++i)
#pragma unroll
      for (int j = 0; j < 4; ++j)
        acc[i][j] = MFMA16(a[i], b[j], acc[i][j]);
  }
#pragma unroll
  for (int i = 0; i < 4; ++i)
#pragma unroll
    for (int j = 0; j < 4; ++j)
#pragma unroll
      for (int q = 0; q < 4; ++q) {
        int R = r0 + i * 16 + kg * 4 + q;
        int col = n0 + j * 16 + fcol;
        C[(size_t)R * OO + col] = acc[i][j][q] + bo[col];
      }
}

extern "C" void kernel_launch(void* const* d_in, const int* in_sizes, int n_in,
                              void* d_out, int out_size, void* d_ws, size_t ws_size,
                              hipStream_t stream) {
  (void)in_sizes; (void)n_in; (void)out_size; (void)ws_size;

  const float* x   = (const float*)d_in[0];
  const float* h0  = (const float*)d_in[1];
  const float* Wzx = (const float*)d_in[2];
  const float* bz  = (const float*)d_in[3];
  const float* Wzh = (const float*)d_in[4];
  const float* Wrx = (const float*)d_in[5];
  const float* br  = (const float*)d_in[6];
  const float* Wrh = (const float*)d_in[7];
  const float* Wgx = (const float*)d_in[8];
  const float* bg  = (const float*)d_in[9];
  const float* Wgh = (const float*)d_in[10];
  const float* Wo  = (const float*)d_in[11];
  const float* bo  = (const float*)d_in[12];
  float* out = (float*)d_out;

  // ws layout (~74 MB)
  u16* Pzh = (u16*)d_ws;            // 6 packed weight groups x 3M elems
  u16* Pzx = Pzh + 3145728;
  u16* Prh = Pzx + 3145728;
  u16* Prx = Prh + 3145728;
  u16* Pgh = Prx + 3145728;
  u16* Pgx = Pgh + 3145728;
  u16* Wob = Pgx + 3145728;         // 1M elems (unpacked bf16)
  u16* xbuf = Wob + 1048576;        // 16.7M elems; doubles as y (in-place)
  u16* hb   = xbuf + 16777216;      // [B][H]
  u16* rhb  = hb + 32768;           // [B][H]
  int* flags = (int*)(rhb + 32768); // 3 layers x 64

  hipMemsetAsync(flags, 0, 3 * NBLK * sizeof(int), stream);

  pack_w<<<3072, 256, 0, stream>>>(Wzh, Pzh, 3);
  pack_w<<<3072, 256, 0, stream>>>(Wzx, Pzx, 3);
  pack_w<<<3072, 256, 0, stream>>>(Wrh, Prh, 3);
  pack_w<<<3072, 256, 0, stream>>>(Wrx, Prx, 3);
  pack_w<<<3072, 256, 0, stream>>>(Wgh, Pgh, 3);
  pack_w<<<3072, 256, 0, stream>>>(Wgx, Pgx, 3);
  convert_bf16<<<256, 256, 0, stream>>>(Wo, Wob, 1048576);
  convert_bf16<<<2048, 256, 0, stream>>>(x, xbuf, 16777216);

  for (int l = 0; l < 3; ++l) {
    gru_layer<<<NBLK, 256, 0, stream>>>(
        xbuf, xbuf,
        Pzh + (size_t)l * 1048576, Pzx + (size_t)l * 1048576,
        Prh + (size_t)l * 1048576, Prx + (size_t)l * 1048576,
        Pgh + (size_t)l * 1048576, Pgx + (size_t)l * 1048576,
        bz + l * 1024, br + l * 1024, bg + l * 1024,
        h0 + l * 1024,
        hb, rhb,
        out + 16777216 + l * 1024,
        flags + l * NBLK);
  }

  out_gemm<<<4096, 64, 0, stream>>>(xbuf, Wob, bo, out);
}

// Round 3
// 15179.330 us; speedup vs baseline: 5.2252x; 3.3850x over previous
//
#include <hip/hip_runtime.h>
#include <hip/hip_bf16.h>
#include <math.h>

// Multilayer GRU: B=32, S=512, H=1024, L=3, O=1024.
// v3: ONE persistent kernel, 192 blocks = 3 layer-groups x 64, layer-wavefront
// pipelining (layer l step t gates on layer l-1 step t). No LDS staging: MFMA
// A-frags loaded directly from coherent global into registers. Per-wave flag
// publish, single-wave poll. g's x-side GEMM hidden under the phase barrier.

#define BB 32
#define SS 512
#define HH 1024
#define LL 3
#define OO 1024
#define SH (SS*HH)

typedef __attribute__((ext_vector_type(8))) short short8;
typedef __attribute__((ext_vector_type(4))) float float4v;
typedef unsigned long long u64;
typedef unsigned int u32;
typedef unsigned short u16;

__device__ __forceinline__ u16 f2bf(float f) {
  union { float f; u32 u; } v; v.f = f;
  return (u16)((v.u + 0x7FFFu + ((v.u >> 16) & 1u)) >> 16);
}

__global__ void convert_bf16(const float* __restrict__ src,
                             u16* __restrict__ dst, int n) {
  int stride = gridDim.x * blockDim.x;
  for (int i = blockIdx.x * blockDim.x + threadIdx.x; i < n; i += stride)
    dst[i] = f2bf(src[i]);
}

// hb[l][b][c] = bf16(h0[b][l][c])
__global__ void init_h(const float* __restrict__ h0, u16* __restrict__ hb) {
  int i = blockIdx.x * 256 + threadIdx.x;           // 98304 total
  int l = i >> 15, r = i & 32767, b = r >> 10, c = r & 1023;
  hb[i] = f2bf(h0[b * 3072 + l * 1024 + c]);
}

// Pack W[nmat][1024][1024] into MFMA B-fragment stream:
// dst[((row>>4)*32+(k>>5))*512 + lane*8 + (k&7)], lane = ((k>>3)&3)*16+(row&15)
__global__ void pack_w(const float* __restrict__ src, u16* __restrict__ dst,
                       int nmat) {
  int stride = gridDim.x * blockDim.x;
  int total = nmat * 1048576;
  for (int i = blockIdx.x * blockDim.x + threadIdx.x; i < total; i += stride) {
    int m = i >> 20, e = i & 1048575;
    int row = e >> 10, k = e & 1023;
    int lane = ((k >> 3) & 3) * 16 + (row & 15);
    int di = ((row >> 4) * 32 + (k >> 5)) * 512 + lane * 8 + (k & 7);
    dst[m * 1048576 + di] = f2bf(src[i]);
  }
}

__device__ __forceinline__ void coh_store_u16(u16* p, u16 v) {
  u32 vv = v;
  asm volatile("global_store_short %0, %1, off sc0 sc1"
               :: "v"(p), "v"(vv) : "memory");
}

__device__ __forceinline__ short8 coh16(const u64* p) {
  union { u64 q[2]; short8 v; } u;
  u.q[0] = __hip_atomic_load(p,     __ATOMIC_RELAXED, __HIP_MEMORY_SCOPE_AGENT);
  u.q[1] = __hip_atomic_load(p + 1, __ATOMIC_RELAXED, __HIP_MEMORY_SCOPE_AGENT);
  return u.v;
}

__device__ __forceinline__ int cohflag(const int* p) {
  return __hip_atomic_load(p, __ATOMIC_RELAXED, __HIP_MEMORY_SCOPE_AGENT);
}

#define MFMA16(a, b, c) __builtin_amdgcn_mfma_f32_16x16x32_bf16(a, b, c, 0, 0, 0)

__launch_bounds__(256, 1)
__global__ void gru_pipe(
    u16* __restrict__ buf0, u16* __restrict__ buf1,
    const u16* __restrict__ Pzh, const u16* __restrict__ Pzx,
    const u16* __restrict__ Prh, const u16* __restrict__ Prx,
    const u16* __restrict__ Pgh, const u16* __restrict__ Pgx,
    const float* __restrict__ bz, const float* __restrict__ br,
    const float* __restrict__ bg, const float* __restrict__ h0,
    u16* __restrict__ hb, u16* __restrict__ rh,
    float* __restrict__ hid, int* __restrict__ flagsD,
    int* __restrict__ flagsP) {
  const int grp = blockIdx.x >> 6;        // layer 0..2
  const int blk = blockIdx.x & 63;        // 16-col tile
  const int tid = threadIdx.x;
  const int lane = tid & 63;
  const int wave = tid >> 6;
  const int mt = wave & 1;                // M-tile: rows 0-15 / 16-31
  const int kh = wave >> 1;               // phase1 side: 0=h, 1=x
  const int fcol = lane & 15, kg = lane >> 4;
  const int arow = mt * 16 + fcol;
  const int crow0 = mt * 16 + kg * 4;
  const int colZ = blk * 16 + fcol;

  const u16* xin = (grp & 1) ? buf1 : buf0;
  u16* yout      = (grp & 1) ? buf0 : buf1;
  const size_t lw = (size_t)grp * 1048576;
  const u16* wZ  = (kh ? Pzx : Pzh) + lw + blk * 16384 + lane * 8;
  const u16* wR  = (kh ? Prx : Prh) + lw + blk * 16384 + lane * 8;
  const u16* wGx = Pgx + lw + blk * 16384 + lane * 8;
  const u16* wGh = Pgh + lw + blk * 16384 + lane * 8;
  u16* hbl = hb + grp * (BB * HH);
  u16* rhl = rh + grp * (BB * HH);
  int* selfD = flagsD + (grp + 1) * 128;
  int* prodD = flagsD + grp * 128;
  int* selfP = flagsP + grp * 128;

  __shared__ float redz[4][2][64], redr[4][2][64], redg[4][2][64];

  float hreg[4] = {0, 0, 0, 0}, zreg[4] = {0, 0, 0, 0};
  float bzv = 0, brv = 0, bgv = 0;
  if (kh == 0) {
#pragma unroll
    for (int q = 0; q < 4; ++q)
      hreg[q] = h0[(crow0 + q) * (LL * HH) + grp * HH + colZ];
    bzv = bz[grp * HH + colZ];
    brv = br[grp * HH + colZ];
    bgv = bg[grp * HH + colZ];
  }

  for (int t = 0; t < SS; ++t) {
    // ---- barrier A: own group finished step t-1; producer finished step t
    if (wave == 0) {
      const int ts = 2 * t, tp = 2 * t + 2;
      while (true) {
        int a0 = cohflag(selfD + lane);
        int a1 = cohflag(selfD + 64 + lane);
        int b0 = cohflag(prodD + lane);
        int b1 = cohflag(prodD + 64 + lane);
        if (__all((a0 >= ts) & (a1 >= ts) & (b0 >= tp) & (b1 >= tp))) break;
      }
    }
    __syncthreads();

    // ---- phase 1: z,r GEMM over this wave's K-side ----------------------
    short8 afr[32];
    {
      const u64* A1 = (kh == 0)
          ? (const u64*)(hbl + arow * HH)
          : (const u64*)(xin + (size_t)arow * SH + (size_t)t * HH);
#pragma unroll
      for (int ks = 0; ks < 32; ++ks) afr[ks] = coh16(A1 + ks * 8 + kg * 2);
    }
    float4v az0 = {0,0,0,0}, az1 = {0,0,0,0};
    float4v ar0 = {0,0,0,0}, ar1 = {0,0,0,0};
#pragma unroll
    for (int ks = 0; ks < 32; ++ks) {
      short8 vz = *(const short8*)(wZ + ks * 512);
      short8 vr = *(const short8*)(wR + ks * 512);
      if (ks & 1) { az1 = MFMA16(afr[ks], vz, az1); ar1 = MFMA16(afr[ks], vr, ar1); }
      else        { az0 = MFMA16(afr[ks], vz, az0); ar0 = MFMA16(afr[ks], vr, ar0); }
    }
    if (kh == 1) {
#pragma unroll
      for (int q = 0; q < 4; ++q) {
        redz[q][mt][lane] = az0[q] + az1[q];
        redr[q][mt][lane] = ar0[q] + ar1[q];
      }
    }
    __syncthreads();

    float4v ag0 = {0,0,0,0}, ag1 = {0,0,0,0};
    if (kh == 0) {
      // finalize z, r; publish rh; per-wave flag
#pragma unroll
      for (int q = 0; q < 4; ++q) {
        float pz = az0[q] + az1[q] + redz[q][mt][lane] + bzv;
        float pr = ar0[q] + ar1[q] + redr[q][mt][lane] + brv;
        zreg[q] = 1.f / (1.f + expf(-pz));
        float rv = 1.f / (1.f + expf(-pr));
        coh_store_u16(rhl + (crow0 + q) * HH + colZ, f2bf(rv * hreg[q]));
      }
      asm volatile("s_waitcnt vmcnt(0)" ::: "memory");
      if (lane == 0)
        __hip_atomic_store(selfP + blk * 2 + mt, 2 * t + 1, __ATOMIC_RELAXED,
                           __HIP_MEMORY_SCOPE_AGENT);
    } else {
      // g's x-side GEMM: hidden under the rh barrier; afr (x) reused
#pragma unroll
      for (int ks = 0; ks < 32; ++ks) {
        short8 vg = *(const short8*)(wGx + ks * 512);
        if (ks & 1) ag1 = MFMA16(afr[ks], vg, ag1);
        else        ag0 = MFMA16(afr[ks], vg, ag0);
      }
    }

    // ---- barrier B: all rh published ------------------------------------
    if (wave == 0) {
      const int ts = 2 * t + 1;
      while (true) {
        int a0 = cohflag(selfP + lane);
        int a1 = cohflag(selfP + 64 + lane);
        if (__all((a0 >= ts) & (a1 >= ts))) break;
      }
    }
    __syncthreads();

    // ---- phase 2: g h-side, K split across kh waves ---------------------
    {
      const u64* A2 = (const u64*)(rhl + arow * HH);
      const int ksb = kh * 16;
      short8 af2[16];
#pragma unroll
      for (int ks = 0; ks < 16; ++ks)
        af2[ks] = coh16(A2 + (ksb + ks) * 8 + kg * 2);
#pragma unroll
      for (int ks = 0; ks < 16; ++ks) {
        short8 vg = *(const short8*)(wGh + (ksb + ks) * 512);
        if (ks & 1) ag1 = MFMA16(af2[ks], vg, ag1);
        else        ag0 = MFMA16(af2[ks], vg, ag0);
      }
    }
    if (kh == 1) {
#pragma unroll
      for (int q = 0; q < 4; ++q) redg[q][mt][lane] = ag0[q] + ag1[q];
    }
    __syncthreads();
    if (kh == 0) {
#pragma unroll
      for (int q = 0; q < 4; ++q) {
        float pg = ag0[q] + ag1[q] + redg[q][mt][lane] + bgv;
        float gv = tanhf(pg);
        float hn = zreg[q] * hreg[q] + (1.f - zreg[q]) * gv;
        hreg[q] = hn;
        u16 hv = f2bf(hn);
        const int row = crow0 + q;
        coh_store_u16(hbl + row * HH + colZ, hv);
        coh_store_u16(yout + (size_t)row * SH + (size_t)t * HH + colZ, hv);
        if (t == SS - 1) hid[row * (LL * HH) + grp * HH + colZ] = hn;
      }
      asm volatile("s_waitcnt vmcnt(0)" ::: "memory");
      if (lane == 0)
        __hip_atomic_store(selfD + blk * 2 + mt, 2 * t + 2, __ATOMIC_RELAXED,
                           __HIP_MEMORY_SCOPE_AGENT);
    }
  }
}

// C[16384,1024] = A[16384,1024](bf16) @ W^T(bf16 rows) + bo
__launch_bounds__(64)
__global__ void out_gemm(const u16* __restrict__ A, const u16* __restrict__ W,
                         const float* __restrict__ bo, float* __restrict__ C) {
  const int lane = threadIdx.x;
  const int nt4 = blockIdx.x & 15;
  const int mt4 = blockIdx.x >> 4;
  const int r0 = mt4 * 64, n0 = nt4 * 64;
  const int fcol = lane & 15, kg = lane >> 4;
  float4v acc[4][4];
#pragma unroll
  for (int i = 0; i < 4; ++i)
#pragma unroll
    for (int j = 0; j < 4; ++j) acc[i][j] = (float4v){0, 0, 0, 0};

  for (int ks = 0; ks < 32; ++ks) {
    short8 a[4], b[4];
#pragma unroll
    for (int i = 0; i < 4; ++i)
      a[i] = *(const short8*)(A + (size_t)(r0 + i * 16 + fcol) * HH + ks * 32 + kg * 8);
#pragma unroll
    for (int j = 0; j < 4; ++j)
      b[j] = *(const short8*)(W + (size_t)(n0 + j * 16 + fcol) * HH + ks * 32 + kg * 8);
#pragma unroll
    for (int i = 0; i < 4; ++i)
#pragma unroll
      for (int j = 0; j < 4; ++j)
        acc[i][j] = MFMA16(a[i], b[j], acc[i][j]);
  }
#pragma unroll
  for (int i = 0; i < 4; ++i)
#pragma unroll
    for (int j = 0; j < 4; ++j)
#pragma unroll
      for (int q = 0; q < 4; ++q) {
        int R = r0 + i * 16 + kg * 4 + q;
        int col = n0 + j * 16 + fcol;
        C[(size_t)R * OO + col] = acc[i][j][q] + bo[col];
      }
}

extern "C" void kernel_launch(void* const* d_in, const int* in_sizes, int n_in,
                              void* d_out, int out_size, void* d_ws, size_t ws_size,
                              hipStream_t stream) {
  (void)in_sizes; (void)n_in; (void)out_size; (void)ws_size;

  const float* x   = (const float*)d_in[0];
  const float* h0  = (const float*)d_in[1];
  const float* Wzx = (const float*)d_in[2];
  const float* bz  = (const float*)d_in[3];
  const float* Wzh = (const float*)d_in[4];
  const float* Wrx = (const float*)d_in[5];
  const float* br  = (const float*)d_in[6];
  const float* Wrh = (const float*)d_in[7];
  const float* Wgx = (const float*)d_in[8];
  const float* bg  = (const float*)d_in[9];
  const float* Wgh = (const float*)d_in[10];
  const float* Wo  = (const float*)d_in[11];
  const float* bo  = (const float*)d_in[12];
  float* out = (float*)d_out;

  // ws layout (~103 MB)
  u16* Pzh = (u16*)d_ws;
  u16* Pzx = Pzh + 3145728;
  u16* Prh = Pzx + 3145728;
  u16* Prx = Prh + 3145728;
  u16* Pgh = Prx + 3145728;
  u16* Pgx = Pgh + 3145728;
  u16* Wob = Pgx + 3145728;            // 1M elems
  u16* buf0 = Wob + 1048576;           // 16.7M elems
  u16* buf1 = buf0 + 16777216;
  u16* hbw  = buf1 + 16777216;         // [3][B][H]
  u16* rhw  = hbw + 3 * BB * HH;       // [3][B][H]
  int* flagsD = (int*)(rhw + 3 * BB * HH);  // 4 groups x 128
  int* flagsP = flagsD + 512;               // 3 groups x 128

  hipMemsetAsync(flagsD, 0x7F, 128 * sizeof(int), stream);   // dummy producer
  hipMemsetAsync(flagsD + 128, 0, 384 * sizeof(int), stream);
  hipMemsetAsync(flagsP, 0, 384 * sizeof(int), stream);

  pack_w<<<3072, 256, 0, stream>>>(Wzh, Pzh, 3);
  pack_w<<<3072, 256, 0, stream>>>(Wzx, Pzx, 3);
  pack_w<<<3072, 256, 0, stream>>>(Wrh, Prh, 3);
  pack_w<<<3072, 256, 0, stream>>>(Wrx, Prx, 3);
  pack_w<<<3072, 256, 0, stream>>>(Wgh, Pgh, 3);
  pack_w<<<3072, 256, 0, stream>>>(Wgx, Pgx, 3);
  convert_bf16<<<256, 256, 0, stream>>>(Wo, Wob, 1048576);
  convert_bf16<<<2048, 256, 0, stream>>>(x, buf0, 16777216);
  init_h<<<384, 256, 0, stream>>>(h0, hbw);

  gru_pipe<<<192, 256, 0, stream>>>(
      buf0, buf1, Pzh, Pzx, Prh, Prx, Pgh, Pgx,
      bz, br, bg, h0, hbw, rhw, out + 16777216, flagsD, flagsP);

  out_gemm<<<4096, 64, 0, stream>>>(buf1, Wob, bo, out);
}